// Round 14
// baseline (1329.224 us; speedup 1.0000x reference)
//
#include <hip/hip_runtime.h>

#define N_NODES 100000
#define N_EDGES 1600000
#define N_GRAPHS 256
#define F_IN 32
#define F_HID 64
#define F_OUT 64

#define TS_BLOCKS 3125          // 12500 waves x 8 nodes = 100000 exactly
#define NXCD 8
#define DPX ((N_NODES + NXCD - 1) / NXCD)

// ---------------- CSR build ----------------
__global__ __launch_bounds__(256) void histogram_xcd(const int* __restrict__ dst,
                                                     int* __restrict__ deg) {
    int xcd = blockIdx.x & (NXCD - 1);
    int sub = blockIdx.x >> 3;
    int nsub = gridDim.x >> 3;
    int d_lo = xcd * DPX;
    int d_hi = min(d_lo + DPX, N_NODES);
    for (int e = sub * blockDim.x + threadIdx.x; e < N_EDGES; e += nsub * blockDim.x) {
        int d = __builtin_nontemporal_load(dst + e);
        if (d >= d_lo && d < d_hi) atomicAdd(&deg[d], 1);
    }
}

__global__ void scan1(const int* __restrict__ deg, int* __restrict__ end_, int* __restrict__ partials) {
    __shared__ int s[256];
    int tid = threadIdx.x;
    int i = blockIdx.x * 256 + tid;
    int v = (i < N_NODES) ? deg[i] : 0;
    s[tid] = v;
    __syncthreads();
#pragma unroll
    for (int off = 1; off < 256; off <<= 1) {
        int t = 0;
        if (tid >= off) t = s[tid - off];
        __syncthreads();
        if (tid >= off) s[tid] += t;
        __syncthreads();
    }
    if (i < N_NODES) end_[i] = s[tid];
    if (tid == 255) partials[blockIdx.x] = s[255];
}

__global__ void scan2(int* __restrict__ partials, int nb) {
    __shared__ int s[512];
    int tid = threadIdx.x;
    int v = (tid < nb) ? partials[tid] : 0;
    s[tid] = v;
    __syncthreads();
#pragma unroll
    for (int off = 1; off < 512; off <<= 1) {
        int t = 0;
        if (tid >= off) t = s[tid - off];
        __syncthreads();
        if (tid >= off) s[tid] += t;
        __syncthreads();
    }
    int excl = (tid > 0) ? s[tid - 1] : 0;
    if (tid < nb) partials[tid] = excl;
}

__global__ void scan3(const int* __restrict__ deg, int* __restrict__ end_,
                      int* __restrict__ cursor, const int* __restrict__ partials) {
    int i = blockIdx.x * 256 + threadIdx.x;
    if (i < N_NODES) {
        int e = end_[i] + partials[blockIdx.x];
        end_[i] = e;
        cursor[i] = e - deg[i];
    }
}

__global__ __launch_bounds__(256) void fill_adj_xcd(const int* __restrict__ src,
                                                    const int* __restrict__ dst,
                                                    int* __restrict__ cursor,
                                                    int* __restrict__ adj) {
    int xcd = blockIdx.x & (NXCD - 1);
    int sub = blockIdx.x >> 3;
    int nsub = gridDim.x >> 3;
    int d_lo = xcd * DPX;
    int d_hi = min(d_lo + DPX, N_NODES);
    for (int e = sub * blockDim.x + threadIdx.x; e < N_EDGES; e += nsub * blockDim.x) {
        int d = __builtin_nontemporal_load(dst + e);
        if (d >= d_lo && d < d_hi) {
            int pos = atomicAdd(&cursor[d], 1);
            adj[pos] = __builtin_nontemporal_load(src + e);
        }
    }
}

// ---------------- float4 gathers ----------------
__global__ __launch_bounds__(256) void gather64_v2(const float* __restrict__ h,
        const int* __restrict__ adj, const int* __restrict__ end_, const int* __restrict__ deg,
        float* __restrict__ agg) {
    int node = (blockIdx.x * blockDim.x + threadIdx.x) >> 6;
    int lane = threadIdx.x & 63;
    if (node >= N_NODES) return;
    int e = end_[node];
    int d = deg[node];
    int s = e - d;
    int q = lane & 15;
    int r = lane >> 4;
    const float4* h4 = (const float4*)h;

    float ax = 0.f, ay = 0.f, az = 0.f, aw = 0.f;
    for (int base = 0; base < d; base += 8) {
        int i0 = base + r;
        int i1 = base + 4 + r;
        if (i0 < d) {
            int s0 = adj[s + i0];
            float4 v = h4[(size_t)s0 * 16 + q];
            ax += v.x; ay += v.y; az += v.z; aw += v.w;
        }
        if (i1 < d) {
            int s1 = adj[s + i1];
            float4 v = h4[(size_t)s1 * 16 + q];
            ax += v.x; ay += v.y; az += v.z; aw += v.w;
        }
    }
#pragma unroll
    for (int off = 16; off < 64; off <<= 1) {
        ax += __shfl_xor(ax, off);
        ay += __shfl_xor(ay, off);
        az += __shfl_xor(az, off);
        aw += __shfl_xor(aw, off);
    }
    if (r == 0) {
        float4 o; o.x = ax; o.y = ay; o.z = az; o.w = aw;
        ((float4*)agg)[(size_t)node * 16 + q] = o;
    }
}

__global__ __launch_bounds__(256) void gather32_v2(const float* __restrict__ xin,
        const int* __restrict__ adj, const int* __restrict__ end_, const int* __restrict__ deg,
        float* __restrict__ agg) {
    int node = (blockIdx.x * blockDim.x + threadIdx.x) >> 6;
    int lane = threadIdx.x & 63;
    if (node >= N_NODES) return;
    int e = end_[node];
    int d = deg[node];
    int s = e - d;
    int q = lane & 7;
    int r = lane >> 3;
    const float4* x4 = (const float4*)xin;

    float ax = 0.f, ay = 0.f, az = 0.f, aw = 0.f;
    for (int base = 0; base < d; base += 16) {
        int i0 = base + r;
        int i1 = base + 8 + r;
        if (i0 < d) {
            int s0 = adj[s + i0];
            float4 v = x4[(size_t)s0 * 8 + q];
            ax += v.x; ay += v.y; az += v.z; aw += v.w;
        }
        if (i1 < d) {
            int s1 = adj[s + i1];
            float4 v = x4[(size_t)s1 * 8 + q];
            ax += v.x; ay += v.y; az += v.z; aw += v.w;
        }
    }
#pragma unroll
    for (int off = 8; off < 64; off <<= 1) {
        ax += __shfl_xor(ax, off);
        ay += __shfl_xor(ay, off);
        az += __shfl_xor(az, off);
        aw += __shfl_xor(aw, off);
    }
    if (r == 0) {
        float4 o; o.x = ax; o.y = ay; o.z = az; o.w = aw;
        ((float4*)agg)[(size_t)node * 8 + q] = o;
    }
}

// -------- k-outer streaming transforms: weights loaded per k-step, dead same step --------
// One wave = 8 consecutive nodes, straight-line (no node loop -> nothing to remat).
// Per k-step: 8 weight scalars (coalesced, L1-hot) + 8 broadcast float4 row loads + 64 FMAs.

#define T2N(KK,N) { float4 a = A[N*16+KK]; float4 xx = X[N*16+KK]; \
    o##N += a.x*w0 + a.y*w1 + a.z*w2 + a.w*w3 + xx.x*v0 + xx.y*v1 + xx.z*v2 + xx.w*v3; }

#define T2K(KK) { \
    float w0 = Wrel[(4*KK+0)*64+lane], w1 = Wrel[(4*KK+1)*64+lane]; \
    float w2 = Wrel[(4*KK+2)*64+lane], w3 = Wrel[(4*KK+3)*64+lane]; \
    float v0 = Wroot[(4*KK+0)*64+lane], v1 = Wroot[(4*KK+1)*64+lane]; \
    float v2 = Wroot[(4*KK+2)*64+lane], v3 = Wroot[(4*KK+3)*64+lane]; \
    T2N(KK,0) T2N(KK,1) T2N(KK,2) T2N(KK,3) T2N(KK,4) T2N(KK,5) T2N(KK,6) T2N(KK,7) }

#define T1N(KK,N) { float4 a = A[N*8+KK]; float4 xx = X[N*8+KK]; \
    o##N += a.x*w0 + a.y*w1 + a.z*w2 + a.w*w3 + xx.x*v0 + xx.y*v1 + xx.z*v2 + xx.w*v3; }

#define T1K(KK) { \
    float w0 = Wrel[(4*KK+0)*64+lane], w1 = Wrel[(4*KK+1)*64+lane]; \
    float w2 = Wrel[(4*KK+2)*64+lane], w3 = Wrel[(4*KK+3)*64+lane]; \
    float v0 = Wroot[(4*KK+0)*64+lane], v1 = Wroot[(4*KK+1)*64+lane]; \
    float v2 = Wroot[(4*KK+2)*64+lane], v3 = Wroot[(4*KK+3)*64+lane]; \
    T1N(KK,0) T1N(KK,1) T1N(KK,2) T1N(KK,3) T1N(KK,4) T1N(KK,5) T1N(KK,6) T1N(KK,7) }

__global__ __launch_bounds__(256) void transform1_s(const float* __restrict__ agg,
        const float* __restrict__ xin,
        const float* __restrict__ Wrel, const float* __restrict__ brel,
        const float* __restrict__ Wroot,
        float* __restrict__ h1) {
    int lane = threadIdx.x & 63;
    int wgid = blockIdx.x * 4 + (threadIdx.x >> 6);
    int n0 = wgid * 8;
    if (n0 >= N_NODES) return;
    const float4* A = (const float4*)(agg + (size_t)n0 * 32);
    const float4* X = (const float4*)(xin + (size_t)n0 * 32);
    float b = brel[lane];
    float o0 = b, o1 = b, o2 = b, o3 = b, o4 = b, o5 = b, o6 = b, o7 = b;

    T1K(0) T1K(1) T1K(2) T1K(3) T1K(4) T1K(5) T1K(6) T1K(7)

    float* H = h1 + (size_t)n0 * 64 + lane;
    H[0 * 64] = tanhf(o0); H[1 * 64] = tanhf(o1);
    H[2 * 64] = tanhf(o2); H[3 * 64] = tanhf(o3);
    H[4 * 64] = tanhf(o4); H[5 * 64] = tanhf(o5);
    H[6 * 64] = tanhf(o6); H[7 * 64] = tanhf(o7);
}

#define POOLSTEP(N) { \
    if (g##N != curg) { atomicAdd(&sums[(size_t)curg * 64 + lane], psum); psum = t##N; curg = g##N; } \
    else psum += t##N; }

__global__ __launch_bounds__(256) void transform2_pool_s(const float* __restrict__ agg,
        const float* __restrict__ h1,
        const float* __restrict__ Wrel, const float* __restrict__ brel,
        const float* __restrict__ Wroot,
        const int* __restrict__ batch,
        float* __restrict__ sums) {
    int lane = threadIdx.x & 63;
    int wgid = blockIdx.x * 4 + (threadIdx.x >> 6);
    int n0 = wgid * 8;
    if (n0 >= N_NODES) return;
    const float4* A = (const float4*)(agg + (size_t)n0 * 64);
    const float4* X = (const float4*)(h1 + (size_t)n0 * 64);
    float b = brel[lane];
    float o0 = b, o1 = b, o2 = b, o3 = b, o4 = b, o5 = b, o6 = b, o7 = b;

    T2K(0) T2K(1) T2K(2) T2K(3) T2K(4) T2K(5) T2K(6) T2K(7)
    T2K(8) T2K(9) T2K(10) T2K(11) T2K(12) T2K(13) T2K(14) T2K(15)

    float t0 = tanhf(o0), t1 = tanhf(o1), t2 = tanhf(o2), t3 = tanhf(o3);
    float t4 = tanhf(o4), t5 = tanhf(o5), t6 = tanhf(o6), t7 = tanhf(o7);
    int g0 = batch[n0 + 0], g1 = batch[n0 + 1], g2 = batch[n0 + 2], g3 = batch[n0 + 3];
    int g4 = batch[n0 + 4], g5 = batch[n0 + 5], g6 = batch[n0 + 6], g7 = batch[n0 + 7];

    float psum = t0;
    int curg = g0;
    POOLSTEP(1) POOLSTEP(2) POOLSTEP(3) POOLSTEP(4) POOLSTEP(5) POOLSTEP(6) POOLSTEP(7)
    atomicAdd(&sums[(size_t)curg * 64 + lane], psum);
}

__global__ void graph_counts(const int* __restrict__ batch, float* __restrict__ counts) {
    int g = threadIdx.x;
    if (g >= N_GRAPHS) return;
    int lo = 0, hi = N_NODES;
    while (lo < hi) { int mid = (lo + hi) >> 1; if (batch[mid] < g) lo = mid + 1; else hi = mid; }
    int start = lo;
    lo = 0; hi = N_NODES;
    while (lo < hi) { int mid = (lo + hi) >> 1; if (batch[mid] <= g) lo = mid + 1; else hi = mid; }
    counts[g] = (float)(lo - start);
}

__global__ void finalize(const float* __restrict__ sums,
                         const float* __restrict__ counts,
                         float* __restrict__ out) {
    int i = blockIdx.x * blockDim.x + threadIdx.x;
    if (i < N_GRAPHS * 64) {
        float c = counts[i >> 6];
        out[i] = sums[i] / fmaxf(c, 1.0f);
    }
}

extern "C" void kernel_launch(void* const* d_in, const int* in_sizes, int n_in,
                              void* d_out, int out_size, void* d_ws, size_t ws_size,
                              hipStream_t stream) {
    const float* x       = (const float*)d_in[0];
    const int*   ei      = (const int*)d_in[1];
    const int*   batch   = (const int*)d_in[2];
    const float* W1_rel  = (const float*)d_in[3];
    const float* b1_rel  = (const float*)d_in[4];
    const float* W1_root = (const float*)d_in[5];
    const float* W2_rel  = (const float*)d_in[6];
    const float* b2_rel  = (const float*)d_in[7];
    const float* W2_root = (const float*)d_in[8];
    float* out = (float*)d_out;

    const int* src = ei;
    const int* dst = ei + N_EDGES;

    // ---- workspace layout (bytes) ----
    char* ws = (char*)d_ws;
    int*   deg      = (int*)(ws + 0);                 // 400000
    float* sums     = (float*)(ws + 400000);          // 65536
    float* counts   = (float*)(ws + 465536);          // 1024
    // ---- zero boundary: 466560 ----
    int*   end_     = (int*)(ws + 466560);            // 400000
    int*   cursor   = (int*)(ws + 866560);            // 400000
    int*   partials = (int*)(ws + 1266560);           // 2048
    int*   adj      = (int*)(ws + 1268608);           // 6400000
    float* aggbuf   = (float*)(ws + 7668608);         // 25600000 (agg1/agg2 shared)
    float* h1       = (float*)(ws + 33268608);        // 25600000

    hipMemsetAsync(d_ws, 0, 466560, stream);

    // ---- CSR build ----
    const int NB_NODE = (N_NODES + 255) / 256;
    histogram_xcd<<<2048, 256, 0, stream>>>(dst, deg);
    scan1<<<NB_NODE, 256, 0, stream>>>(deg, end_, partials);
    scan2<<<1, 512, 0, stream>>>(partials, NB_NODE);
    scan3<<<NB_NODE, 256, 0, stream>>>(deg, end_, cursor, partials);
    fill_adj_xcd<<<2048, 256, 0, stream>>>(src, dst, cursor, adj);

    // ---- layer 1 ----
    gather32_v2<<<(N_NODES * 64 + 255) / 256, 256, 0, stream>>>(x, adj, end_, deg, aggbuf);
    transform1_s<<<TS_BLOCKS, 256, 0, stream>>>(aggbuf, x, W1_rel, b1_rel, W1_root, h1);

    // ---- layer 2 ----
    gather64_v2<<<(N_NODES * 64 + 255) / 256, 256, 0, stream>>>(h1, adj, end_, deg, aggbuf);
    transform2_pool_s<<<TS_BLOCKS, 256, 0, stream>>>(aggbuf, h1, W2_rel, b2_rel, W2_root, batch, sums);

    graph_counts<<<1, 256, 0, stream>>>(batch, counts);
    finalize<<<(N_GRAPHS * 64 + 255) / 256, 256, 0, stream>>>(sums, counts, out);
}

// Round 15
// 374.008 us; speedup vs baseline: 3.5540x; 3.5540x over previous
//
#include <hip/hip_runtime.h>

#define N_NODES 100000
#define N_EDGES 1600000
#define N_GRAPHS 256
#define F_IN 32
#define F_HID 64
#define F_OUT 64

#define T_WAVES 8192
#define NODES_PER_WAVE ((N_NODES + T_WAVES - 1) / T_WAVES)   // 13
#define T2_BLOCKS 3125          // 12500 waves x 8 nodes: more in-flight streams
#define T2_WAVES (T2_BLOCKS * 4)
#define NODES_PER_WAVE2 ((N_NODES + T2_WAVES - 1) / T2_WAVES)  // 8
#define NXCD 8
#define DPX ((N_NODES + NXCD - 1) / NXCD)

// ---------------- CSR build ----------------
__global__ __launch_bounds__(256) void histogram_xcd(const int* __restrict__ dst,
                                                     int* __restrict__ deg) {
    int xcd = blockIdx.x & (NXCD - 1);
    int sub = blockIdx.x >> 3;
    int nsub = gridDim.x >> 3;
    int d_lo = xcd * DPX;
    int d_hi = min(d_lo + DPX, N_NODES);
    for (int e = sub * blockDim.x + threadIdx.x; e < N_EDGES; e += nsub * blockDim.x) {
        int d = __builtin_nontemporal_load(dst + e);
        if (d >= d_lo && d < d_hi) atomicAdd(&deg[d], 1);
    }
}

__global__ void scan1(const int* __restrict__ deg, int* __restrict__ end_, int* __restrict__ partials) {
    __shared__ int s[256];
    int tid = threadIdx.x;
    int i = blockIdx.x * 256 + tid;
    int v = (i < N_NODES) ? deg[i] : 0;
    s[tid] = v;
    __syncthreads();
#pragma unroll
    for (int off = 1; off < 256; off <<= 1) {
        int t = 0;
        if (tid >= off) t = s[tid - off];
        __syncthreads();
        if (tid >= off) s[tid] += t;
        __syncthreads();
    }
    if (i < N_NODES) end_[i] = s[tid];
    if (tid == 255) partials[blockIdx.x] = s[255];
}

__global__ void scan2(int* __restrict__ partials, int nb) {
    __shared__ int s[512];
    int tid = threadIdx.x;
    int v = (tid < nb) ? partials[tid] : 0;
    s[tid] = v;
    __syncthreads();
#pragma unroll
    for (int off = 1; off < 512; off <<= 1) {
        int t = 0;
        if (tid >= off) t = s[tid - off];
        __syncthreads();
        if (tid >= off) s[tid] += t;
        __syncthreads();
    }
    int excl = (tid > 0) ? s[tid - 1] : 0;
    if (tid < nb) partials[tid] = excl;
}

__global__ void scan3(const int* __restrict__ deg, int* __restrict__ end_,
                      int* __restrict__ cursor, const int* __restrict__ partials) {
    int i = blockIdx.x * 256 + threadIdx.x;
    if (i < N_NODES) {
        int e = end_[i] + partials[blockIdx.x];
        end_[i] = e;
        cursor[i] = e - deg[i];
    }
}

__global__ __launch_bounds__(256) void fill_adj_xcd(const int* __restrict__ src,
                                                    const int* __restrict__ dst,
                                                    int* __restrict__ cursor,
                                                    int* __restrict__ adj) {
    int xcd = blockIdx.x & (NXCD - 1);
    int sub = blockIdx.x >> 3;
    int nsub = gridDim.x >> 3;
    int d_lo = xcd * DPX;
    int d_hi = min(d_lo + DPX, N_NODES);
    for (int e = sub * blockDim.x + threadIdx.x; e < N_EDGES; e += nsub * blockDim.x) {
        int d = __builtin_nontemporal_load(dst + e);
        if (d >= d_lo && d < d_hi) {
            int pos = atomicAdd(&cursor[d], 1);
            adj[pos] = __builtin_nontemporal_load(src + e);
        }
    }
}

// ---------------- float4 gathers ----------------
__global__ __launch_bounds__(256) void gather64_v2(const float* __restrict__ h,
        const int* __restrict__ adj, const int* __restrict__ end_, const int* __restrict__ deg,
        float* __restrict__ agg) {
    int node = (blockIdx.x * blockDim.x + threadIdx.x) >> 6;
    int lane = threadIdx.x & 63;
    if (node >= N_NODES) return;
    int e = end_[node];
    int d = deg[node];
    int s = e - d;
    int q = lane & 15;
    int r = lane >> 4;
    const float4* h4 = (const float4*)h;

    float ax = 0.f, ay = 0.f, az = 0.f, aw = 0.f;
    for (int base = 0; base < d; base += 8) {
        int i0 = base + r;
        int i1 = base + 4 + r;
        if (i0 < d) {
            int s0 = adj[s + i0];
            float4 v = h4[(size_t)s0 * 16 + q];
            ax += v.x; ay += v.y; az += v.z; aw += v.w;
        }
        if (i1 < d) {
            int s1 = adj[s + i1];
            float4 v = h4[(size_t)s1 * 16 + q];
            ax += v.x; ay += v.y; az += v.z; aw += v.w;
        }
    }
#pragma unroll
    for (int off = 16; off < 64; off <<= 1) {
        ax += __shfl_xor(ax, off);
        ay += __shfl_xor(ay, off);
        az += __shfl_xor(az, off);
        aw += __shfl_xor(aw, off);
    }
    if (r == 0) {
        float4 o; o.x = ax; o.y = ay; o.z = az; o.w = aw;
        ((float4*)agg)[(size_t)node * 16 + q] = o;
    }
}

__global__ __launch_bounds__(256) void gather32_v2(const float* __restrict__ xin,
        const int* __restrict__ adj, const int* __restrict__ end_, const int* __restrict__ deg,
        float* __restrict__ agg) {
    int node = (blockIdx.x * blockDim.x + threadIdx.x) >> 6;
    int lane = threadIdx.x & 63;
    if (node >= N_NODES) return;
    int e = end_[node];
    int d = deg[node];
    int s = e - d;
    int q = lane & 7;
    int r = lane >> 3;
    const float4* x4 = (const float4*)xin;

    float ax = 0.f, ay = 0.f, az = 0.f, aw = 0.f;
    for (int base = 0; base < d; base += 16) {
        int i0 = base + r;
        int i1 = base + 8 + r;
        if (i0 < d) {
            int s0 = adj[s + i0];
            float4 v = x4[(size_t)s0 * 8 + q];
            ax += v.x; ay += v.y; az += v.z; aw += v.w;
        }
        if (i1 < d) {
            int s1 = adj[s + i1];
            float4 v = x4[(size_t)s1 * 8 + q];
            ax += v.x; ay += v.y; az += v.z; aw += v.w;
        }
    }
#pragma unroll
    for (int off = 8; off < 64; off <<= 1) {
        ax += __shfl_xor(ax, off);
        ay += __shfl_xor(ay, off);
        az += __shfl_xor(az, off);
        aw += __shfl_xor(aw, off);
    }
    if (r == 0) {
        float4 o; o.x = ax; o.y = ay; o.z = az; o.w = aw;
        ((float4*)agg)[(size_t)node * 8 + q] = o;
    }
}

// ---------------- transforms (R11 structure: remat weights are L1-hits; the
// stream of agg/h1 rows is the real load — hide it with more waves) ----------------
__global__ __launch_bounds__(256) void transform1_reg(const float* __restrict__ agg,
        const float* __restrict__ xin,
        const float* __restrict__ Wrel, const float* __restrict__ brel,
        const float* __restrict__ Wroot,
        float* __restrict__ h1) {
    int lane = threadIdx.x & 63;
    int wgid = __builtin_amdgcn_readfirstlane(blockIdx.x * 4 + (threadIdx.x >> 6));
    int n0 = wgid * NODES_PER_WAVE;
    if (n0 >= N_NODES) return;
    int n1 = min(n0 + NODES_PER_WAVE, N_NODES);

    float wrel[32], wroot[32];
#pragma unroll
    for (int k = 0; k < 32; ++k) {
        wrel[k] = Wrel[k * 64 + lane];
        wroot[k] = Wroot[k * 64 + lane];
    }
    float b = brel[lane];

    for (int node = n0; node < n1; ++node) {
        const float4* ar = (const float4*)(agg + (size_t)node * 32);
        const float4* xr = (const float4*)(xin + (size_t)node * 32);
        float o = b;
#pragma unroll
        for (int kk = 0; kk < 8; ++kk) {
            float4 a4 = ar[kk];
            float4 x4 = xr[kk];
            o += a4.x * wrel[kk * 4 + 0] + a4.y * wrel[kk * 4 + 1]
               + a4.z * wrel[kk * 4 + 2] + a4.w * wrel[kk * 4 + 3];
            o += x4.x * wroot[kk * 4 + 0] + x4.y * wroot[kk * 4 + 1]
               + x4.z * wroot[kk * 4 + 2] + x4.w * wroot[kk * 4 + 3];
        }
        h1[(size_t)node * 64 + lane] = tanhf(o);
    }
}

__global__ __launch_bounds__(256, 2) void transform2_pool_reg(const float* __restrict__ agg,
        const float* __restrict__ h1,
        const float* __restrict__ Wrel, const float* __restrict__ brel,
        const float* __restrict__ Wroot,
        const int* __restrict__ batch,
        float* __restrict__ sums) {
    int lane = threadIdx.x & 63;
    int wgid = __builtin_amdgcn_readfirstlane(blockIdx.x * 4 + (threadIdx.x >> 6));
    int n0 = wgid * NODES_PER_WAVE2;
    if (n0 >= N_NODES) return;
    int n1 = min(n0 + NODES_PER_WAVE2, N_NODES);

    float wrel[64], wroot[64];
#pragma unroll
    for (int k = 0; k < 64; ++k) {
        wrel[k] = Wrel[k * 64 + lane];
        wroot[k] = Wroot[k * 64 + lane];
    }
    float b = brel[lane];

    float psum = 0.0f;
    int curg = batch[n0];
    int node = n0;
    for (; node + 1 < n1; node += 2) {
        const float4* ar0 = (const float4*)(agg + (size_t)node * 64);
        const float4* xr0 = (const float4*)(h1 + (size_t)node * 64);
        const float4* ar1 = (const float4*)(agg + (size_t)(node + 1) * 64);
        const float4* xr1 = (const float4*)(h1 + (size_t)(node + 1) * 64);
        float o0 = b, o1 = b;
#pragma unroll
        for (int kk = 0; kk < 16; ++kk) {
            float4 a0 = ar0[kk];
            float4 x0 = xr0[kk];
            float4 a1 = ar1[kk];
            float4 x1 = xr1[kk];
            o0 += a0.x * wrel[kk * 4 + 0] + a0.y * wrel[kk * 4 + 1]
                + a0.z * wrel[kk * 4 + 2] + a0.w * wrel[kk * 4 + 3];
            o1 += a1.x * wrel[kk * 4 + 0] + a1.y * wrel[kk * 4 + 1]
                + a1.z * wrel[kk * 4 + 2] + a1.w * wrel[kk * 4 + 3];
            o0 += x0.x * wroot[kk * 4 + 0] + x0.y * wroot[kk * 4 + 1]
                + x0.z * wroot[kk * 4 + 2] + x0.w * wroot[kk * 4 + 3];
            o1 += x1.x * wroot[kk * 4 + 0] + x1.y * wroot[kk * 4 + 1]
                + x1.z * wroot[kk * 4 + 2] + x1.w * wroot[kk * 4 + 3];
        }
        float h20 = tanhf(o0);
        float h21 = tanhf(o1);
        int g0 = batch[node];
        int g1 = batch[node + 1];
        if (g0 != curg) {
            atomicAdd(&sums[(size_t)curg * 64 + lane], psum);
            psum = 0.0f;
            curg = g0;
        }
        psum += h20;
        if (g1 != curg) {
            atomicAdd(&sums[(size_t)curg * 64 + lane], psum);
            psum = 0.0f;
            curg = g1;
        }
        psum += h21;
    }
    if (node < n1) {
        const float4* ar = (const float4*)(agg + (size_t)node * 64);
        const float4* xr = (const float4*)(h1 + (size_t)node * 64);
        float o = b;
#pragma unroll
        for (int kk = 0; kk < 16; ++kk) {
            float4 a4 = ar[kk];
            float4 x4 = xr[kk];
            o += a4.x * wrel[kk * 4 + 0] + a4.y * wrel[kk * 4 + 1]
               + a4.z * wrel[kk * 4 + 2] + a4.w * wrel[kk * 4 + 3];
            o += x4.x * wroot[kk * 4 + 0] + x4.y * wroot[kk * 4 + 1]
               + x4.z * wroot[kk * 4 + 2] + x4.w * wroot[kk * 4 + 3];
        }
        float h2 = tanhf(o);
        int g = batch[node];
        if (g != curg) {
            atomicAdd(&sums[(size_t)curg * 64 + lane], psum);
            psum = 0.0f;
            curg = g;
        }
        psum += h2;
    }
    atomicAdd(&sums[(size_t)curg * 64 + lane], psum);
}

__global__ void graph_counts(const int* __restrict__ batch, float* __restrict__ counts) {
    int g = threadIdx.x;
    if (g >= N_GRAPHS) return;
    int lo = 0, hi = N_NODES;
    while (lo < hi) { int mid = (lo + hi) >> 1; if (batch[mid] < g) lo = mid + 1; else hi = mid; }
    int start = lo;
    lo = 0; hi = N_NODES;
    while (lo < hi) { int mid = (lo + hi) >> 1; if (batch[mid] <= g) lo = mid + 1; else hi = mid; }
    counts[g] = (float)(lo - start);
}

__global__ void finalize(const float* __restrict__ sums,
                         const float* __restrict__ counts,
                         float* __restrict__ out) {
    int i = blockIdx.x * blockDim.x + threadIdx.x;
    if (i < N_GRAPHS * 64) {
        float c = counts[i >> 6];
        out[i] = sums[i] / fmaxf(c, 1.0f);
    }
}

extern "C" void kernel_launch(void* const* d_in, const int* in_sizes, int n_in,
                              void* d_out, int out_size, void* d_ws, size_t ws_size,
                              hipStream_t stream) {
    const float* x       = (const float*)d_in[0];
    const int*   ei      = (const int*)d_in[1];
    const int*   batch   = (const int*)d_in[2];
    const float* W1_rel  = (const float*)d_in[3];
    const float* b1_rel  = (const float*)d_in[4];
    const float* W1_root = (const float*)d_in[5];
    const float* W2_rel  = (const float*)d_in[6];
    const float* b2_rel  = (const float*)d_in[7];
    const float* W2_root = (const float*)d_in[8];
    float* out = (float*)d_out;

    const int* src = ei;
    const int* dst = ei + N_EDGES;

    // ---- workspace layout (bytes) ----
    char* ws = (char*)d_ws;
    int*   deg      = (int*)(ws + 0);                 // 400000
    float* sums     = (float*)(ws + 400000);          // 65536
    float* counts   = (float*)(ws + 465536);          // 1024
    // ---- zero boundary: 466560 ----
    int*   end_     = (int*)(ws + 466560);            // 400000
    int*   cursor   = (int*)(ws + 866560);            // 400000
    int*   partials = (int*)(ws + 1266560);           // 2048
    int*   adj      = (int*)(ws + 1268608);           // 6400000
    float* aggbuf   = (float*)(ws + 7668608);         // 25600000 (agg1/agg2 shared)
    float* h1       = (float*)(ws + 33268608);        // 25600000

    hipMemsetAsync(d_ws, 0, 466560, stream);

    // ---- CSR build ----
    const int NB_NODE = (N_NODES + 255) / 256;
    histogram_xcd<<<2048, 256, 0, stream>>>(dst, deg);
    scan1<<<NB_NODE, 256, 0, stream>>>(deg, end_, partials);
    scan2<<<1, 512, 0, stream>>>(partials, NB_NODE);
    scan3<<<NB_NODE, 256, 0, stream>>>(deg, end_, cursor, partials);
    fill_adj_xcd<<<2048, 256, 0, stream>>>(src, dst, cursor, adj);

    // ---- layer 1 ----
    gather32_v2<<<(N_NODES * 64 + 255) / 256, 256, 0, stream>>>(x, adj, end_, deg, aggbuf);
    transform1_reg<<<T_WAVES / 4, 256, 0, stream>>>(aggbuf, x, W1_rel, b1_rel, W1_root, h1);

    // ---- layer 2 ----
    gather64_v2<<<(N_NODES * 64 + 255) / 256, 256, 0, stream>>>(h1, adj, end_, deg, aggbuf);
    transform2_pool_reg<<<T2_BLOCKS, 256, 0, stream>>>(aggbuf, h1, W2_rel, b2_rel, W2_root, batch, sums);

    graph_counts<<<1, 256, 0, stream>>>(batch, counts);
    finalize<<<(N_GRAPHS * 64 + 255) / 256, 256, 0, stream>>>(sums, counts, out);
}